// Round 7
// baseline (176.999 us; speedup 1.0000x reference)
//
#include <hip/hip_runtime.h>
#include <math.h>

namespace {

constexpr int NATOM = 512;
constexpr float STEP = 10.0f / 63.0f;

typedef float f32x4 __attribute__((ext_vector_type(4)));
typedef short s16x8 __attribute__((ext_vector_type(8)));

struct Ptrs { const float* p[19]; };

// input index map:
// 0 geometry [512,3]; 1 x0 [512,32,1]; 2 x1 [512,32,3]
// then per net q in {f0,fa,fb,fc}: 3+4q w1[64,64]; 4+4q b1[64]; 5+4q w2[32,64]; 6+4q b2[32]

__device__ __forceinline__ unsigned f2bf(float f) {
  union { float f; unsigned u; } v; v.f = f;
  return (v.u + 0x7fffu + ((v.u >> 16) & 1u)) >> 16;  // RNE
}

// No min-waves clause (R5 lesson: (512,4) pledge -> 64-VGPR cap -> 360 MB spill).
__global__ __launch_bounds__(512)
void tfn_fused(Ptrs A, float* __restrict__ out) {
  const int a    = blockIdx.x;
  const int tid  = threadIdx.x;
  const int wv   = tid >> 6;
  const int w    = wv & 3;        // net: 0=f0 1=fa 2=fb 3=fc
  const int mh   = wv >> 2;       // b-half of the 32-neighbor tile
  const int lane = tid & 63;
  const int ln   = lane & 15;
  const int hi   = lane >> 4;     // 0..3

  // ---------------- LDS (61 KB; LDS-pipe ISSUE COUNT is the kernel's bottleneck) ----------------
  __shared__ __align__(16) short rbf_frag[2][2][2][64][8]; // [dbuf][kt][mt][lane][8] bf16 frag-order
  __shared__ __align__(16) short h_s[4 * 32 * 72];         // per-net h, XOR-swizzled chunks (wave-private)
  __shared__ __align__(16) float xall[2][32][132];         // [dbuf][b][4c+{x0,x1x,x1y,x1z}] stride 132 (4 mod 32)
  __shared__ __align__(16) float scr[4][16][8];            // mh-pair combine

  const float* __restrict__ geom = A.p[0];
  const float* __restrict__ x0g  = A.p[1];
  const float* __restrict__ x1g  = A.p[2];

  // ---------------- persistent register B-fragments (weights, bf16) ----------------
  s16x8 w1f[4][2];
  {
    const float* w1p = A.p[3 + 4 * w];
    #pragma unroll
    for (int nt = 0; nt < 4; ++nt)
      #pragma unroll
      for (int kt = 0; kt < 2; ++kt) {
        const float* src = w1p + (nt * 16 + ln) * 64 + kt * 32 + hi * 8;
        s16x8 f;
        #pragma unroll
        for (int i = 0; i < 8; ++i) f[i] = (short)f2bf(src[i]);
        w1f[nt][kt] = f;
      }
  }
  float b1v[4];
  {
    const float* b1p = A.p[4 + 4 * w];
    #pragma unroll
    for (int nt = 0; nt < 4; ++nt) b1v[nt] = b1p[nt * 16 + ln];
  }
  s16x8 w2f[2][2];
  {
    const float* w2p = A.p[5 + 4 * w];
    #pragma unroll
    for (int nt = 0; nt < 2; ++nt)
      #pragma unroll
      for (int kt = 0; kt < 2; ++kt) {
        const float* src = w2p + (nt * 16 + ln) * 64 + kt * 32 + hi * 8;
        s16x8 f;
        #pragma unroll
        for (int i = 0; i < 8; ++i) f[i] = (short)f2bf(src[i]);
        w2f[nt][kt] = f;
      }
  }
  float b2v[2];
  {
    const float* b2p = A.p[6 + 4 * w];
    b2v[0] = b2p[ln]; b2v[1] = b2p[16 + ln];
  }

  const float gax = geom[3*a+0], gay = geom[3*a+1], gaz = geom[3*a+2];

  const int sb = tid >> 4;        // staging row (neighbor in tile)
  const int sc = tid & 15;        // staging channel group
  const int bl4 = mh * 16 + hi * 4;

  float av[8] = {0.f,0.f,0.f,0.f,0.f,0.f,0.f,0.f};

  for (int t = 0; t < 16; ++t) {
    const int b0  = t * 32;
    const int buf = t & 1;

    // ---- geometry prefetch for stage-3 u-recompute (L1-resident, replaces u_lds b128 reads) ----
    float gxe[4], gye[4], gze[4];
    if (w != 0) {
      const float* gp = geom + 3 * (b0 + bl4);
      #pragma unroll
      for (int e = 0; e < 4; ++e) {
        gxe[e] = gp[3*e+0]; gye[e] = gp[3*e+1]; gze[e] = gp[3*e+2];
      }
    }

    // ---------------- Phase A: staging (xall interleaved b128 writes, rbf frag-order) ----------------
    {
      // xall[b][4c..4c+3] = {x0[b][c], x1[b][c][0..2]} : 8 global b32 -> 2 LDS b128 per thread
      const float* x0row = x0g + (b0 + sb) * 32;
      const float* x1row = x1g + (b0 + sb) * 96;
      f32x4 v0, v1;
      v0[0] = x0row[sc];
      v0[1] = x1row[3*sc+0]; v0[2] = x1row[3*sc+1]; v0[3] = x1row[3*sc+2];
      v1[0] = x0row[sc+16];
      v1[1] = x1row[3*(sc+16)+0]; v1[2] = x1row[3*(sc+16)+1]; v1[3] = x1row[3*(sc+16)+2];
      *(f32x4*)&xall[buf][sb][4*sc]        = v0;
      *(f32x4*)&xall[buf][sb][4*(sc+16)]   = v1;

      const int bb = tid & 31;          // neighbor in tile
      const int kq = tid >> 5;          // rbf quad 0..15 (4 centers each)
      const int bg = b0 + bb;
      const float dx = gax - geom[3*bg+0];
      const float dy = gay - geom[3*bg+1];
      const float dz = gaz - geom[3*bg+2];
      const float r2 = dx*dx + dy*dy + dz*dz;
      const float dij = sqrtf(fmaxf(r2, 1e-8f));
      const float d0 = dij - STEP * (float)(4 * kq);
      const float d1 = d0 - STEP, d2 = d0 - 2.f*STEP, d3 = d0 - 3.f*STEP;
      const unsigned lo  = f2bf(__expf(-10.f*d0*d0)) | (f2bf(__expf(-10.f*d1*d1)) << 16);
      const unsigned hi2 = f2bf(__expf(-10.f*d2*d2)) | (f2bf(__expf(-10.f*d3*d3)) << 16);
      uint2 pk; pk.x = lo; pk.y = hi2;
      // frag address: kt=kq>>3, mt=bb>>4, fraglane=((kq>>1)&3)*16+(bb&15), half=kq&1
      *(uint2*)&rbf_frag[buf][kq >> 3][bb >> 4][((kq >> 1) & 3) * 16 + (bb & 15)][(kq & 1) * 4] = pk;
    }
    __syncthreads();   // the only barrier per tile (2-deep dbuf makes it race-free)

    // ---------------- Stage 1: H = relu(RBF . W1^T + b1) ----------------
    const s16x8 af0 = *(const s16x8*)&rbf_frag[buf][0][mh][lane][0];  // lane-linear, conflict-free
    const s16x8 af1 = *(const s16x8*)&rbf_frag[buf][1][mh][lane][0];
    f32x4 acc1[4] = {};
    #pragma unroll
    for (int nt = 0; nt < 4; ++nt)
      acc1[nt] = __builtin_amdgcn_mfma_f32_16x16x32_bf16(af0, w1f[nt][0], acc1[nt], 0, 0, 0);
    #pragma unroll
    for (int nt = 0; nt < 4; ++nt)
      acc1[nt] = __builtin_amdgcn_mfma_f32_16x16x32_bf16(af1, w1f[nt][1], acc1[nt], 0, 0, 0);
    // bias+relu+cvt, XOR-swizzled scatter (wave-private rows -> no barrier)
    #pragma unroll
    for (int nt = 0; nt < 4; ++nt) {
      const int j = nt * 16 + ln;
      #pragma unroll
      for (int r = 0; r < 4; ++r) {
        const int bl = mh * 16 + hi * 4 + r;
        h_s[(w * 32 + bl) * 72 + (((j >> 3) ^ (bl & 7)) << 3) + (j & 7)] =
            (short)f2bf(fmaxf(acc1[nt][r] + b1v[nt], 0.0f));
      }
    }

    // ---------------- Stage 2: RAD = H . W2^T + b2 (rad stays in registers) ----------------
    const int hbase = (w * 32 + mh * 16 + ln) * 72;
    const s16x8 a20 = *(const s16x8*)&h_s[hbase + (((0 + hi) ^ (ln & 7)) << 3)];
    const s16x8 a21 = *(const s16x8*)&h_s[hbase + (((4 + hi) ^ (ln & 7)) << 3)];
    f32x4 acc2[2] = {};
    acc2[0] = __builtin_amdgcn_mfma_f32_16x16x32_bf16(a20, w2f[0][0], acc2[0], 0, 0, 0);
    acc2[1] = __builtin_amdgcn_mfma_f32_16x16x32_bf16(a20, w2f[1][0], acc2[1], 0, 0, 0);
    acc2[0] = __builtin_amdgcn_mfma_f32_16x16x32_bf16(a21, w2f[0][1], acc2[0], 0, 0, 0);
    acc2[1] = __builtin_amdgcn_mfma_f32_16x16x32_bf16(a21, w2f[1][1], acc2[1], 0, 0, 0);
    float rad0[4], rad1[4];
    #pragma unroll
    for (int e = 0; e < 4; ++e) { rad0[e] = acc2[0][e] + b2v[0]; rad1[e] = acc2[1][e] + b2v[1]; }
    // lane (ln,hi) holds rad[c=ln | 16+ln][b = 16mh+4hi .. +3] -- exactly stage-3 ownership.

    // ---------------- Stage 3: 2 b128 xall reads per e; u recomputed in registers ----------------
    if (w == 0) {            // f0: out0_a += r0*x0 ; out1_b += r0*x1
      #pragma unroll
      for (int e = 0; e < 4; ++e) {
        const int b = bl4 + e;
        const f32x4 xv0 = *(const f32x4*)&xall[buf][b][4*ln];
        const f32x4 xv1 = *(const f32x4*)&xall[buf][b][4*(16+ln)];
        const float r = rad0[e], s = rad1[e];
        av[0] = fmaf(r, xv0[0], av[0]);
        av[1] = fmaf(r, xv0[1], av[1]);
        av[2] = fmaf(r, xv0[2], av[2]);
        av[3] = fmaf(r, xv0[3], av[3]);
        av[4] = fmaf(s, xv1[0], av[4]);
        av[5] = fmaf(s, xv1[1], av[5]);
        av[6] = fmaf(s, xv1[2], av[6]);
        av[7] = fmaf(s, xv1[3], av[7]);
      }
    } else {
      #pragma unroll
      for (int e = 0; e < 4; ++e) {
        const int b = bl4 + e;
        const f32x4 xv0 = *(const f32x4*)&xall[buf][b][4*ln];
        const f32x4 xv1 = *(const f32x4*)&xall[buf][b][4*(16+ln)];
        const float dx = gax - gxe[e], dy = gay - gye[e], dz = gaz - gze[e];
        const float r2 = fmaf(dx, dx, fmaf(dy, dy, dz * dz));
        const float rs = 1.0f / sqrtf(r2 + 1e-8f);   // unit = rij*rs; rij=0 diag -> 0 (self-mask free)
        if (w == 1) {        // fa: out1_a += (ra*x0*rs) * d
          const float t0 = rad0[e] * xv0[0] * rs;
          av[0] = fmaf(t0, dx, av[0]); av[1] = fmaf(t0, dy, av[1]); av[2] = fmaf(t0, dz, av[2]);
          const float t1 = rad1[e] * xv1[0] * rs;
          av[3] = fmaf(t1, dx, av[3]); av[4] = fmaf(t1, dy, av[4]); av[5] = fmaf(t1, dz, av[5]);
        } else if (w == 2) { // fb: out0_b += rb*rs*(d . x1)
          const float dot0 = fmaf(dx, xv0[1], fmaf(dy, xv0[2], dz * xv0[3]));
          av[0] = fmaf(rad0[e] * rs, dot0, av[0]);
          const float dot1 = fmaf(dx, xv1[1], fmaf(dy, xv1[2], dz * xv1[3]));
          av[1] = fmaf(rad1[e] * rs, dot1, av[1]);
        } else {             // fc: out1_c += rc*rs*(d x x1)
          const float q0 = rad0[e] * rs, q1 = rad1[e] * rs;
          av[0] = fmaf(q0, fmaf(dy, xv0[3], -(dz * xv0[2])), av[0]);
          av[1] = fmaf(q0, fmaf(dz, xv0[1], -(dx * xv0[3])), av[1]);
          av[2] = fmaf(q0, fmaf(dx, xv0[2], -(dy * xv0[1])), av[2]);
          av[3] = fmaf(q1, fmaf(dy, xv1[3], -(dz * xv1[2])), av[3]);
          av[4] = fmaf(q1, fmaf(dz, xv1[1], -(dx * xv1[3])), av[4]);
          av[5] = fmaf(q1, fmaf(dx, xv1[2], -(dy * xv1[1])), av[5]);
        }
      }
    }
  }

  // ---------------- reduce over hi (shfl) and mh (LDS), then store ----------------
  #pragma unroll
  for (int q = 0; q < 8; ++q) {
    av[q] += __shfl_xor(av[q], 16);
    av[q] += __shfl_xor(av[q], 32);
  }
  if (mh == 1 && hi == 0) {
    #pragma unroll
    for (int q = 0; q < 8; ++q) scr[w][ln][q] = av[q];
  }
  __syncthreads();
  if (mh == 0 && hi == 0) {
    #pragma unroll
    for (int q = 0; q < 8; ++q) av[q] += scr[w][ln][q];
    float* o1 = out + NATOM * 64 + a * 288;   // out1 [512][96][3]
    if (w == 0) {
      out[a * 64 + ln]      = av[0];
      o1[(32 + ln) * 3 + 0] = av[1]; o1[(32 + ln) * 3 + 1] = av[2]; o1[(32 + ln) * 3 + 2] = av[3];
      out[a * 64 + 16 + ln] = av[4];
      o1[(48 + ln) * 3 + 0] = av[5]; o1[(48 + ln) * 3 + 1] = av[6]; o1[(48 + ln) * 3 + 2] = av[7];
    } else if (w == 1) {
      o1[(     ln) * 3 + 0] = av[0]; o1[(     ln) * 3 + 1] = av[1]; o1[(     ln) * 3 + 2] = av[2];
      o1[(16 + ln) * 3 + 0] = av[3]; o1[(16 + ln) * 3 + 1] = av[4]; o1[(16 + ln) * 3 + 2] = av[5];
    } else if (w == 2) {
      out[a * 64 + 32 + ln] = av[0];
      out[a * 64 + 48 + ln] = av[1];
    } else {
      o1[(64 + ln) * 3 + 0] = av[0]; o1[(64 + ln) * 3 + 1] = av[1]; o1[(64 + ln) * 3 + 2] = av[2];
      o1[(80 + ln) * 3 + 0] = av[3]; o1[(80 + ln) * 3 + 1] = av[4]; o1[(80 + ln) * 3 + 2] = av[5];
    }
  }
}

} // namespace

extern "C" void kernel_launch(void* const* d_in, const int* in_sizes, int n_in,
                              void* d_out, int out_size, void* d_ws, size_t ws_size,
                              hipStream_t stream) {
  (void)in_sizes; (void)n_in; (void)d_ws; (void)ws_size; (void)out_size;
  Ptrs A;
  for (int i = 0; i < 19; ++i) A.p[i] = (const float*)d_in[i];
  tfn_fused<<<dim3(NATOM), dim3(512), 0, stream>>>(A, (float*)d_out);
}